// Round 1
// 211.870 us; speedup vs baseline: 1.0221x; 1.0221x over previous
//
#include <hip/hip_runtime.h>

// Problem constants: codes [16,128,128,128] f32, segmap [16,4,1,256,256] i32,
// fc_w [512,128] f32, fc_b [512] f32.  Nearest 256->128 == sample (2y,2x).
//
// R3 lesson: per-block __threadfence (agent scope) on gfx950 costs ~200us
//   (L2 writeback per block across 8 XCDs) — last-block fusion abandoned.
// R4 lesson: 3->2 dispatch fusion bought only ~2us but introduced an
//   unresolved post-timing divergence — abandoned. Proven R2 structure:
//   3 kernels, no atomics on the data path, no fences.
// R5 (this round): fc widened to 256 blocks x 128 thr (4x CU coverage,
//   scale-after-dot removes a barrier); masked_sum selects -> cvt_f32_ubyte
//   multipliers + uint2 mask loads + 8 independent acc chains.
#define B    16
#define S    4
#define F    128
#define HW   16384   // 128*128 low-res pixels
#define HWIN 65536   // 256*256 segmap pixels
#define OUT  512
#define PBLK 16      // mask_pack blocks per batch

// ---------------- Kernel 0: pack segment masks + per-block partial counts --
// grid = B*PBLK, 256 threads; thread packs 4 low-res pixels into one uchar4
// (bit s = segment-s membership). Per-block counts -> pcounts[block][s]
// (no global atomics, no memset needed).  UNCHANGED from R2 (proven).
__global__ __launch_bounds__(256) void mask_pack_kernel(
    const int* __restrict__ segmap,
    unsigned char* __restrict__ pmask,
    int* __restrict__ pcounts) {
    const int b   = blockIdx.x >> 4;
    const int t   = threadIdx.x;
    const int pbase = (blockIdx.x & 15) * 1024 + t * 4;  // 4 px, same row
    const int y = pbase >> 7;
    const int x = pbase & 127;
    const int* sm = segmap + (size_t)b * (S * HWIN);
    const int row = (2 * y) * 256 + 2 * x;   // 32B-aligned -> int4 ok

    unsigned char outb[4] = {0, 0, 0, 0};
    int cnt[S];
#pragma unroll
    for (int s = 0; s < S; ++s) {
        const int4 l0 = *(const int4*)(sm + s * HWIN + row);
        const int4 l1 = *(const int4*)(sm + s * HWIN + row + 4);
        int c = 0;
        if (l0.x) { outb[0] |= (1 << s); c++; }
        if (l0.z) { outb[1] |= (1 << s); c++; }
        if (l1.x) { outb[2] |= (1 << s); c++; }
        if (l1.z) { outb[3] |= (1 << s); c++; }
        cnt[s] = c;
    }
    *(uchar4*)(pmask + (size_t)b * HW + pbase) =
        make_uchar4(outb[0], outb[1], outb[2], outb[3]);

    // block-reduce the 4 counts: wave shuffle, then LDS across 4 waves
    __shared__ int sc[4][S];
#pragma unroll
    for (int s = 0; s < S; ++s) {
#pragma unroll
        for (int off = 32; off > 0; off >>= 1)
            cnt[s] += __shfl_down(cnt[s], off);
    }
    const int wave = t >> 6;
    if ((t & 63) == 0) {
#pragma unroll
        for (int s = 0; s < S; ++s) sc[wave][s] = cnt[s];
    }
    __syncthreads();
    if (t < S)
        pcounts[blockIdx.x * S + t] = sc[0][t] + sc[1][t] + sc[2][t] + sc[3][t];
}

// ---------------- Kernel 1: masked segment sums (the 128 MiB pass) ---------
// grid = B*F = 2048 blocks, 256 threads. Block (b,f) streams the 64 KiB plane
// codes[b,f,:,:]. Thread handles 2 ADJACENT float4s per stripe so the 8 mask
// bytes arrive as one uint2 load. Mask bit -> {0.0,1.0} multiplier via
// (float)((sel >> 8k) & 0xff)  (v_cvt_f32_ubyteN + v_fmac, ~2.5 instr/term
// vs ~4 for the cndmask form). 8 independent accumulator chains.
__global__ __launch_bounds__(256) void masked_sum_kernel(
    const float* __restrict__ codes,
    const unsigned char* __restrict__ pmask,
    float* __restrict__ sums) {
    const int bf = blockIdx.x;
    const int b  = bf >> 7;
    const int t  = threadIdx.x;
    const float4* cp = (const float4*)(codes + (size_t)bf * HW);
    const unsigned char* mpb = pmask + (size_t)b * HW;

    float accA[S] = {0.f, 0.f, 0.f, 0.f};
    float accB[S] = {0.f, 0.f, 0.f, 0.f};
#pragma unroll
    for (int i = 0; i < 8; ++i) {
        const int idx = i * 512 + t * 2;           // adjacent float4 pair
        const float4 c0 = cp[idx];
        const float4 c1 = cp[idx + 1];
        const uint2  mm = *(const uint2*)(mpb + (size_t)idx * 4);  // 8 mask bytes
        const unsigned m0 = mm.x;                  // bytes = masks for c0.xyzw
        const unsigned m1 = mm.y;                  // bytes = masks for c1.xyzw
#pragma unroll
        for (int s = 0; s < S; ++s) {
            const unsigned selA = (m0 >> s) & 0x01010101u;  // bytes in {0,1}
            const unsigned selB = (m1 >> s) & 0x01010101u;
            accA[s] = fmaf((float)(selA & 0xffu),         c0.x, accA[s]);
            accA[s] = fmaf((float)((selA >> 8) & 0xffu),  c0.y, accA[s]);
            accA[s] = fmaf((float)((selA >> 16) & 0xffu), c0.z, accA[s]);
            accA[s] = fmaf((float)(selA >> 24),           c0.w, accA[s]);
            accB[s] = fmaf((float)(selB & 0xffu),         c1.x, accB[s]);
            accB[s] = fmaf((float)((selB >> 8) & 0xffu),  c1.y, accB[s]);
            accB[s] = fmaf((float)((selB >> 16) & 0xffu), c1.z, accB[s]);
            accB[s] = fmaf((float)(selB >> 24),           c1.w, accB[s]);
        }
    }
    float a[S];
#pragma unroll
    for (int s = 0; s < S; ++s) a[s] = accA[s] + accB[s];

#pragma unroll
    for (int off = 32; off > 0; off >>= 1) {
#pragma unroll
        for (int s = 0; s < S; ++s) a[s] += __shfl_down(a[s], off);
    }
    __shared__ float part[4][S];
    const int wave = t >> 6;
    if ((t & 63) == 0) {
#pragma unroll
        for (int s = 0; s < S; ++s) part[wave][s] = a[s];
    }
    __syncthreads();
    if (t < S) {
        const int f = bf & 127;
        sums[(size_t)(b * S + t) * F + f] =
            part[0][t] + part[1][t] + part[2][t] + part[3][t];
    }
}

// ---------------- Kernel 2: counts finalize + feats @ W^T + b --------------
// grid = B*S*4 = 256 blocks (4x the CU coverage of the old 64-block version),
// 128 threads = one output element each. Count summed per-thread via scalar
// loads (uniform address); scaling applied AFTER the dot product so only one
// barrier is needed:  out = (sums . w) * sinv + bias  ==  (sums*sinv) . w + b.
__global__ __launch_bounds__(128) void fc_kernel(
    const float* __restrict__ sums,
    const int* __restrict__ pcounts,
    const float* __restrict__ fc_w,
    const float* __restrict__ fc_b,
    float* __restrict__ out) {
    const int blk = blockIdx.x;
    const int bs  = blk >> 2;           // = b*S + s
    const int q   = blk & 3;            // output quarter
    const int b   = bs >> 2;
    const int s   = bs & 3;
    const int t   = threadIdx.x;

    int c = 0;
#pragma unroll
    for (int k = 0; k < PBLK; ++k)
        c += pcounts[(b * PBLK + k) * S + s];     // uniform -> s_load
    const float sinv = (c > 0) ? (1.0f / (float)c) : 0.0f;

    __shared__ float feats[F];
    feats[t] = sums[(size_t)bs * F + t];          // raw sums (unscaled)
    __syncthreads();

    const int r = q * 128 + t;                    // output row 0..511
    const float4* w4 = (const float4*)(fc_w + (size_t)r * F);
    const float4* f4 = (const float4*)feats;
    float acc = 0.f;
#pragma unroll
    for (int i = 0; i < F / 4; ++i) {
        const float4 wv = w4[i];
        const float4 fv = f4[i];
        acc = fmaf(wv.x, fv.x, acc);
        acc = fmaf(wv.y, fv.y, acc);
        acc = fmaf(wv.z, fv.z, acc);
        acc = fmaf(wv.w, fv.w, acc);
    }
    out[(size_t)bs * OUT + r] = acc * sinv + fc_b[r];
}

extern "C" void kernel_launch(void* const* d_in, const int* in_sizes, int n_in,
                              void* d_out, int out_size, void* d_ws, size_t ws_size,
                              hipStream_t stream) {
    const float* codes  = (const float*)d_in[0];
    const int*   segmap = (const int*)d_in[1];
    const float* fc_w   = (const float*)d_in[2];
    const float* fc_b   = (const float*)d_in[3];
    float* out = (float*)d_out;

    // ws layout: [pmask 256 KiB][pcounts 4 KiB][sums 32 KiB]
    unsigned char* pmask   = (unsigned char*)d_ws;
    int*           pcounts = (int*)((char*)d_ws + (size_t)B * HW);
    float*         sums    = (float*)((char*)d_ws + (size_t)B * HW + B * PBLK * S * 4);

    mask_pack_kernel<<<B * PBLK, 256, 0, stream>>>(segmap, pmask, pcounts);
    masked_sum_kernel<<<B * F, 256, 0, stream>>>(codes, pmask, sums);
    fc_kernel<<<B * S * 4, 128, 0, stream>>>(sums, pcounts, fc_w, fc_b, out);
}

// Round 2
// 198.284 us; speedup vs baseline: 1.0921x; 1.0685x over previous
//
#include <hip/hip_runtime.h>

// Problem constants: codes [16,128,128,128] f32, segmap [16,4,1,256,256] i32,
// fc_w [512,128] f32, fc_b [512] f32.  Nearest 256->128 == sample (2y,2x).
//
// R3 lesson: per-block __threadfence (agent scope) on gfx950 costs ~200us
//   (L2 writeback per block across 8 XCDs) — last-block fusion abandoned.
// R4 lesson: 3->2 dispatch fusion bought only ~2us but introduced an
//   unresolved post-timing divergence — abandoned. Proven R2 structure:
//   3 kernels, no atomics on the data path, no fences.
// R5: fc widened to 256 blocks (4x CU coverage, scale-after-dot, 1 barrier);
//   masked_sum selects -> cvt_f32_ubyte multipliers. dur 216.5 -> 211.9.
// R6 (this round): restore fully-coalesced {t, t+256} codes layout (R5's
//   adjacent-pair layout made dwordx4 loads stride-32B); nontemporal loads
//   on the single-use streams (codes, segmap); pmask stays cached (128x reuse).
#define B    16
#define S    4
#define F    128
#define HW   16384   // 128*128 low-res pixels
#define HWIN 65536   // 256*256 segmap pixels
#define OUT  512
#define PBLK 16      // mask_pack blocks per batch

typedef float vf4 __attribute__((ext_vector_type(4)));
typedef int   vi4 __attribute__((ext_vector_type(4)));

// ---------------- Kernel 0: pack segment masks + per-block partial counts --
// grid = B*PBLK, 256 threads; thread packs 4 low-res pixels into one uchar4
// (bit s = segment-s membership). Per-block counts -> pcounts[block][s]
// (no global atomics, no memset needed). R2 structure + nt loads.
__global__ __launch_bounds__(256) void mask_pack_kernel(
    const int* __restrict__ segmap,
    unsigned char* __restrict__ pmask,
    int* __restrict__ pcounts) {
    const int b   = blockIdx.x >> 4;
    const int t   = threadIdx.x;
    const int pbase = (blockIdx.x & 15) * 1024 + t * 4;  // 4 px, same row
    const int y = pbase >> 7;
    const int x = pbase & 127;
    const int* sm = segmap + (size_t)b * (S * HWIN);
    const int row = (2 * y) * 256 + 2 * x;   // 32B-aligned -> int4 ok

    unsigned char outb[4] = {0, 0, 0, 0};
    int cnt[S];
#pragma unroll
    for (int s = 0; s < S; ++s) {
        const vi4 l0 = __builtin_nontemporal_load((const vi4*)(sm + s * HWIN + row));
        const vi4 l1 = __builtin_nontemporal_load((const vi4*)(sm + s * HWIN + row + 4));
        int c = 0;
        if (l0.x) { outb[0] |= (1 << s); c++; }
        if (l0.z) { outb[1] |= (1 << s); c++; }
        if (l1.x) { outb[2] |= (1 << s); c++; }
        if (l1.z) { outb[3] |= (1 << s); c++; }
        cnt[s] = c;
    }
    *(uchar4*)(pmask + (size_t)b * HW + pbase) =
        make_uchar4(outb[0], outb[1], outb[2], outb[3]);

    // block-reduce the 4 counts: wave shuffle, then LDS across 4 waves
    __shared__ int sc[4][S];
#pragma unroll
    for (int s = 0; s < S; ++s) {
#pragma unroll
        for (int off = 32; off > 0; off >>= 1)
            cnt[s] += __shfl_down(cnt[s], off);
    }
    const int wave = t >> 6;
    if ((t & 63) == 0) {
#pragma unroll
        for (int s = 0; s < S; ++s) sc[wave][s] = cnt[s];
    }
    __syncthreads();
    if (t < S)
        pcounts[blockIdx.x * S + t] = sc[0][t] + sc[1][t] + sc[2][t] + sc[3][t];
}

// ---------------- Kernel 1: masked segment sums (the 128 MiB pass) ---------
// grid = B*F = 2048 blocks, 256 threads. Block (b,f) streams the 64 KiB plane
// codes[b,f,:,:] as 2 fully-coalesced dwordx4/iter (lane stride 16B) + one
// packed-mask word per float4. Mask bit -> {0.0,1.0} multiplier via
// (float)((sel >> 8k) & 0xff)  (v_cvt_f32_ubyteN + v_fmac). 8 acc chains.
__global__ __launch_bounds__(256) void masked_sum_kernel(
    const float* __restrict__ codes,
    const unsigned char* __restrict__ pmask,
    float* __restrict__ sums) {
    const int bf = blockIdx.x;
    const int b  = bf >> 7;
    const int t  = threadIdx.x;
    const vf4* cp = (const vf4*)(codes + (size_t)bf * HW);
    const unsigned* mp = (const unsigned*)(pmask + (size_t)b * HW);

    float accA[S] = {0.f, 0.f, 0.f, 0.f};
    float accB[S] = {0.f, 0.f, 0.f, 0.f};
#pragma unroll
    for (int i = 0; i < 8; ++i) {
        const int idx = i * 512 + t;               // contiguous per instr
        const vf4 c0 = __builtin_nontemporal_load(cp + idx);
        const vf4 c1 = __builtin_nontemporal_load(cp + idx + 256);
        const unsigned m0 = mp[idx];               // bytes = masks for c0
        const unsigned m1 = mp[idx + 256];         // bytes = masks for c1
#pragma unroll
        for (int s = 0; s < S; ++s) {
            const unsigned selA = (m0 >> s) & 0x01010101u;  // bytes in {0,1}
            const unsigned selB = (m1 >> s) & 0x01010101u;
            accA[s] = fmaf((float)(selA & 0xffu),         c0.x, accA[s]);
            accA[s] = fmaf((float)((selA >> 8) & 0xffu),  c0.y, accA[s]);
            accA[s] = fmaf((float)((selA >> 16) & 0xffu), c0.z, accA[s]);
            accA[s] = fmaf((float)(selA >> 24),           c0.w, accA[s]);
            accB[s] = fmaf((float)(selB & 0xffu),         c1.x, accB[s]);
            accB[s] = fmaf((float)((selB >> 8) & 0xffu),  c1.y, accB[s]);
            accB[s] = fmaf((float)((selB >> 16) & 0xffu), c1.z, accB[s]);
            accB[s] = fmaf((float)(selB >> 24),           c1.w, accB[s]);
        }
    }
    float a[S];
#pragma unroll
    for (int s = 0; s < S; ++s) a[s] = accA[s] + accB[s];

#pragma unroll
    for (int off = 32; off > 0; off >>= 1) {
#pragma unroll
        for (int s = 0; s < S; ++s) a[s] += __shfl_down(a[s], off);
    }
    __shared__ float part[4][S];
    const int wave = t >> 6;
    if ((t & 63) == 0) {
#pragma unroll
        for (int s = 0; s < S; ++s) part[wave][s] = a[s];
    }
    __syncthreads();
    if (t < S) {
        const int f = bf & 127;
        sums[(size_t)(b * S + t) * F + f] =
            part[0][t] + part[1][t] + part[2][t] + part[3][t];
    }
}

// ---------------- Kernel 2: counts finalize + feats @ W^T + b --------------
// grid = B*S*4 = 256 blocks, 128 threads = one output element each. Count
// summed per-thread via uniform scalar loads; scaling applied AFTER the dot
// product so only one barrier is needed: (sums . w) * sinv + bias.
__global__ __launch_bounds__(128) void fc_kernel(
    const float* __restrict__ sums,
    const int* __restrict__ pcounts,
    const float* __restrict__ fc_w,
    const float* __restrict__ fc_b,
    float* __restrict__ out) {
    const int blk = blockIdx.x;
    const int bs  = blk >> 2;           // = b*S + s
    const int q   = blk & 3;            // output quarter
    const int b   = bs >> 2;
    const int s   = bs & 3;
    const int t   = threadIdx.x;

    int c = 0;
#pragma unroll
    for (int k = 0; k < PBLK; ++k)
        c += pcounts[(b * PBLK + k) * S + s];     // uniform -> s_load
    const float sinv = (c > 0) ? (1.0f / (float)c) : 0.0f;

    __shared__ float feats[F];
    feats[t] = sums[(size_t)bs * F + t];          // raw sums (unscaled)
    __syncthreads();

    const int r = q * 128 + t;                    // output row 0..511
    const float4* w4 = (const float4*)(fc_w + (size_t)r * F);
    const float4* f4 = (const float4*)feats;
    float acc = 0.f;
#pragma unroll
    for (int i = 0; i < F / 4; ++i) {
        const float4 wv = w4[i];
        const float4 fv = f4[i];
        acc = fmaf(wv.x, fv.x, acc);
        acc = fmaf(wv.y, fv.y, acc);
        acc = fmaf(wv.z, fv.z, acc);
        acc = fmaf(wv.w, fv.w, acc);
    }
    out[(size_t)bs * OUT + r] = acc * sinv + fc_b[r];
}

extern "C" void kernel_launch(void* const* d_in, const int* in_sizes, int n_in,
                              void* d_out, int out_size, void* d_ws, size_t ws_size,
                              hipStream_t stream) {
    const float* codes  = (const float*)d_in[0];
    const int*   segmap = (const int*)d_in[1];
    const float* fc_w   = (const float*)d_in[2];
    const float* fc_b   = (const float*)d_in[3];
    float* out = (float*)d_out;

    // ws layout: [pmask 256 KiB][pcounts 4 KiB][sums 32 KiB]
    unsigned char* pmask   = (unsigned char*)d_ws;
    int*           pcounts = (int*)((char*)d_ws + (size_t)B * HW);
    float*         sums    = (float*)((char*)d_ws + (size_t)B * HW + B * PBLK * S * 4);

    mask_pack_kernel<<<B * PBLK, 256, 0, stream>>>(segmap, pmask, pcounts);
    masked_sum_kernel<<<B * F, 256, 0, stream>>>(codes, pmask, sums);
    fc_kernel<<<B * S * 4, 128, 0, stream>>>(sums, pcounts, fc_w, fc_b, out);
}